// Round 1
// baseline (2213.805 us; speedup 1.0000x reference)
//
#include <hip/hip_runtime.h>

// Sizes (fixed by the problem)
#define BB   256
#define SEQ  512
#define HOR  32
#define NK   8192
#define AVL  544   // SEQ + HORIZON
#define NL1  64
#define HID  128
#define G4   512   // 4*HID

__device__ __forceinline__ float bcast(float v, int l) {
    return __uint_as_float(__builtin_amdgcn_readlane(__float_as_uint(v), (unsigned)l));
}
__device__ __forceinline__ float sigm(float x) { return 1.0f / (1.0f + expf(-x)); }

// ---------------------------------------------------------------------------
// K1: dist[256][8192] = input[256][512] @ akey[8192][512]^T   (NT GEMM, fp32)
// tile 64(M) x 128(N) x 32(K), 256 threads, 4x8 micro-tile
// ---------------------------------------------------------------------------
__global__ __launch_bounds__(256) void k_dist(const float* __restrict__ A,
                                              const float* __restrict__ Bm,
                                              float* __restrict__ C) {
    __shared__ float As[32][68];    // [k][m], +pad: 68*4B row, 16B-aligned cols
    __shared__ float Bs[32][132];   // [k][n]
    const int n0 = blockIdx.x * 128;
    const int m0 = blockIdx.y * 64;
    const int tid = threadIdx.x;
    const int tx = tid & 15;   // n
    const int ty = tid >> 4;   // m
    const int lm = tid >> 3;        // 0..31
    const int lk = (tid & 7) * 4;   // 0..28
    float acc[4][8];
#pragma unroll
    for (int i = 0; i < 4; ++i)
#pragma unroll
        for (int j = 0; j < 8; ++j) acc[i][j] = 0.0f;

    for (int kt = 0; kt < 512; kt += 32) {
        __syncthreads();
#pragma unroll
        for (int r = 0; r < 2; ++r) {
            int m = lm + 32 * r;
            float4 v = *(const float4*)&A[(size_t)(m0 + m) * 512 + kt + lk];
            As[lk + 0][m] = v.x; As[lk + 1][m] = v.y;
            As[lk + 2][m] = v.z; As[lk + 3][m] = v.w;
        }
#pragma unroll
        for (int r = 0; r < 4; ++r) {
            int n = lm + 32 * r;
            float4 v = *(const float4*)&Bm[(size_t)(n0 + n) * 512 + kt + lk];
            Bs[lk + 0][n] = v.x; Bs[lk + 1][n] = v.y;
            Bs[lk + 2][n] = v.z; Bs[lk + 3][n] = v.w;
        }
        __syncthreads();
#pragma unroll
        for (int k = 0; k < 32; ++k) {
            float4 a4 = *(const float4*)&As[k][ty * 4];
            float4 b0 = *(const float4*)&Bs[k][tx * 8];
            float4 b1 = *(const float4*)&Bs[k][tx * 8 + 4];
            float av[4] = {a4.x, a4.y, a4.z, a4.w};
            float bv[8] = {b0.x, b0.y, b0.z, b0.w, b1.x, b1.y, b1.z, b1.w};
#pragma unroll
            for (int i = 0; i < 4; ++i)
#pragma unroll
                for (int j = 0; j < 8; ++j)
                    acc[i][j] = fmaf(av[i], bv[j], acc[i][j]);
        }
    }
#pragma unroll
    for (int i = 0; i < 4; ++i) {
        size_t row = (size_t)(m0 + ty * 4 + i) * 8192 + n0 + tx * 8;
        *(float4*)&C[row]     = make_float4(acc[i][0], acc[i][1], acc[i][2], acc[i][3]);
        *(float4*)&C[row + 4] = make_float4(acc[i][4], acc[i][5], acc[i][6], acc[i][7]);
    }
}

// ---------------------------------------------------------------------------
// K2: per-row argmax (first index on ties) -> set 0 -> softmax, in place
// ---------------------------------------------------------------------------
__global__ __launch_bounds__(256) void k_softmax(float* __restrict__ D) {
    __shared__ float row[8192];
    __shared__ float rv[256];
    __shared__ int   ri[256];
    const int b = blockIdx.x, tid = threadIdx.x;
    float* dr = D + (size_t)b * 8192;
    for (int i = tid; i < 2048; i += 256)
        *(float4*)&row[i * 4] = *(const float4*)&dr[i * 4];
    __syncthreads();

    float bv = -INFINITY; int bi = 0x7fffffff;
    for (int i = tid; i < 8192; i += 256) {
        float v = row[i];
        if (v > bv || (v == bv && i < bi)) { bv = v; bi = i; }
    }
    rv[tid] = bv; ri[tid] = bi;
    __syncthreads();
    for (int s = 128; s > 0; s >>= 1) {
        if (tid < s) {
            float ov = rv[tid + s]; int oi = ri[tid + s];
            if (ov > rv[tid] || (ov == rv[tid] && oi < ri[tid])) { rv[tid] = ov; ri[tid] = oi; }
        }
        __syncthreads();
    }
    if (tid == 0) row[ri[0]] = 0.0f;
    __syncthreads();

    float m = -INFINITY;
    for (int i = tid; i < 8192; i += 256) m = fmaxf(m, row[i]);
    rv[tid] = m;
    __syncthreads();
    for (int s = 128; s > 0; s >>= 1) {
        if (tid < s) rv[tid] = fmaxf(rv[tid], rv[tid + s]);
        __syncthreads();
    }
    const float M = rv[0];
    __syncthreads();

    float ssum = 0.0f;
    for (int i = tid; i < 8192; i += 256) {
        float e = expf(row[i] - M);
        row[i] = e;
        ssum += e;
    }
    rv[tid] = ssum;
    __syncthreads();
    for (int s = 128; s > 0; s >>= 1) {
        if (tid < s) rv[tid] += rv[tid + s];
        __syncthreads();
    }
    const float inv = 1.0f / rv[0];
    for (int i = tid; i < 2048; i += 256) {
        float4 v = *(float4*)&row[i * 4];
        v.x *= inv; v.y *= inv; v.z *= inv; v.w *= inv;
        *(float4*)&dr[i * 4] = v;
    }
}

// ---------------------------------------------------------------------------
// K3: hist[256][544] += a[256][8192] @ aval[8192][544]  (NN GEMM, split-K=8)
// tile 64x64x32, 256 threads, 4x4 micro-tile, atomicAdd epilogue
// ---------------------------------------------------------------------------
__global__ __launch_bounds__(256) void k_hist(const float* __restrict__ A,
                                              const float* __restrict__ Bm,
                                              float* __restrict__ C) {
    __shared__ float As[32][68];  // [k][m] transposed
    __shared__ float Bs[32][68];  // [k][n] direct
    const int n0 = blockIdx.x * 64;
    const int m0 = blockIdx.y * 64;
    const int kz = blockIdx.z;
    const int tid = threadIdx.x;
    const int tx = tid & 15, ty = tid >> 4;
    const int lr = tid >> 3;
    const int lq = (tid & 7) * 4;
    float acc[4][4];
#pragma unroll
    for (int i = 0; i < 4; ++i)
#pragma unroll
        for (int j = 0; j < 4; ++j) acc[i][j] = 0.0f;

    const int k_lo = kz * 1024, k_hi = k_lo + 1024;
    for (int kt = k_lo; kt < k_hi; kt += 32) {
        __syncthreads();
#pragma unroll
        for (int r = 0; r < 2; ++r) {
            int m = lr + 32 * r;
            float4 v = *(const float4*)&A[(size_t)(m0 + m) * 8192 + kt + lq];
            As[lq + 0][m] = v.x; As[lq + 1][m] = v.y;
            As[lq + 2][m] = v.z; As[lq + 3][m] = v.w;
        }
#pragma unroll
        for (int r = 0; r < 2; ++r) {
            int kk = (tid >> 4) + 16 * r;
            int nq = (tid & 15) * 4;
            float4 v = make_float4(0.f, 0.f, 0.f, 0.f);
            if (n0 + nq < 544)
                v = *(const float4*)&Bm[(size_t)(kt + kk) * 544 + n0 + nq];
            *(float4*)&Bs[kk][nq] = v;
        }
        __syncthreads();
#pragma unroll
        for (int k = 0; k < 32; ++k) {
            float4 a4 = *(const float4*)&As[k][ty * 4];
            float4 b4 = *(const float4*)&Bs[k][tx * 4];
            float av[4] = {a4.x, a4.y, a4.z, a4.w};
            float bv[4] = {b4.x, b4.y, b4.z, b4.w};
#pragma unroll
            for (int i = 0; i < 4; ++i)
#pragma unroll
                for (int j = 0; j < 4; ++j)
                    acc[i][j] = fmaf(av[i], bv[j], acc[i][j]);
        }
    }
#pragma unroll
    for (int i = 0; i < 4; ++i)
#pragma unroll
        for (int j = 0; j < 4; ++j) {
            int n = n0 + tx * 4 + j;
            if (n < 544)
                atomicAdd(&C[(size_t)(m0 + ty * 4 + i) * 544 + n], acc[i][j]);
        }
}

// ---------------------------------------------------------------------------
// K4: x[b][t][o] = tanh(b1[o] + W1[o][0]*input[b][t] + sum_j W1[o][1+j]*hist[b][t+j])
// ---------------------------------------------------------------------------
__global__ __launch_bounds__(256) void k_xfeat(const float* __restrict__ inp,
                                               const float* __restrict__ hist,
                                               const float* __restrict__ W1,
                                               const float* __restrict__ b1,
                                               float* __restrict__ X) {
    __shared__ float w[33 * 64];  // w[k*64+o]
    __shared__ float bl[64];
    __shared__ float il[128];
    __shared__ float hl[160];
    const int t0 = blockIdx.x * 128;
    const int b  = blockIdx.y;
    const int tid = threadIdx.x;
    for (int idx = tid; idx < 2112; idx += 256) {
        int o = idx / 33, k = idx % 33;
        w[k * 64 + o] = W1[idx];
    }
    if (tid < 64) bl[tid] = b1[tid];
    if (tid < 128) il[tid] = inp[(size_t)b * 512 + t0 + tid];
    for (int i = tid; i < 159; i += 256) hl[i] = hist[(size_t)b * 544 + t0 + i];
    __syncthreads();
    const int o = tid & 63, tq = tid >> 6;
    for (int it = 0; it < 32; ++it) {
        int tl = it * 4 + tq;
        float acc = fmaf(il[tl], w[o], bl[o]);
#pragma unroll
        for (int j = 0; j < 32; ++j)
            acc = fmaf(hl[tl + j], w[(1 + j) * 64 + o], acc);
        X[(size_t)(b * 512 + t0 + tl) * 64 + o] = tanhf(acc);
    }
}

// ---------------------------------------------------------------------------
// K5: LSTM layer 0, fused input-projection. 1 block per batch row.
// thread g owns gate row g: Wih0[g][0:64] + Whh0[g][0:128] register-resident.
// h/x broadcast via v_readlane -> v_fmac(sgpr).
// ---------------------------------------------------------------------------
__global__ __launch_bounds__(512, 2) void k_lstm0(const float* __restrict__ X,
                                                  const float* __restrict__ Wih,
                                                  const float* __restrict__ Whh,
                                                  const float* __restrict__ bih,
                                                  const float* __restrict__ bhh,
                                                  float* __restrict__ H0) {
    __shared__ float hl[128];
    __shared__ float gl[512];
    const int b = blockIdx.x;
    const int g = threadIdx.x;
    const int lane = g & 63;
    float wih[64], whh[128];
#pragma unroll
    for (int k = 0; k < 64; ++k) wih[k] = Wih[(size_t)g * 64 + k];
#pragma unroll
    for (int j = 0; j < 128; ++j) whh[j] = Whh[(size_t)g * 128 + j];
    const float bias = bih[g] + bhh[g];
    float c = 0.0f;
    if (g < 128) hl[g] = 0.0f;
    __syncthreads();
    const float* xb = X + (size_t)b * 512 * 64;
    float* hb = H0 + (size_t)b * 512 * 128;
    float vx = xb[lane];
    for (int t = 0; t < 512; ++t) {
        float vxn = xb[(size_t)(t + 1) * 64 + lane];  // prefetch (padded)
        float vh0 = hl[lane];
        float vh1 = hl[64 + lane];
        float a0 = 0.f, a1 = 0.f, a2 = 0.f, a3 = 0.f;
#pragma unroll
        for (int k = 0; k < 64; k += 4) {
            a0 = fmaf(bcast(vx, k + 0), wih[k + 0], a0);
            a1 = fmaf(bcast(vx, k + 1), wih[k + 1], a1);
            a2 = fmaf(bcast(vx, k + 2), wih[k + 2], a2);
            a3 = fmaf(bcast(vx, k + 3), wih[k + 3], a3);
        }
#pragma unroll
        for (int j = 0; j < 64; j += 4) {
            a0 = fmaf(bcast(vh0, j + 0), whh[j + 0], a0);
            a1 = fmaf(bcast(vh0, j + 1), whh[j + 1], a1);
            a2 = fmaf(bcast(vh0, j + 2), whh[j + 2], a2);
            a3 = fmaf(bcast(vh0, j + 3), whh[j + 3], a3);
        }
#pragma unroll
        for (int j = 0; j < 64; j += 4) {
            a0 = fmaf(bcast(vh1, j + 0), whh[64 + j + 0], a0);
            a1 = fmaf(bcast(vh1, j + 1), whh[64 + j + 1], a1);
            a2 = fmaf(bcast(vh1, j + 2), whh[64 + j + 2], a2);
            a3 = fmaf(bcast(vh1, j + 3), whh[64 + j + 3], a3);
        }
        gl[g] = bias + ((a0 + a1) + (a2 + a3));
        __syncthreads();
        if (g < 128) {
            float iv = sigm(gl[g]);
            float fv = sigm(gl[128 + g]);
            float gv = tanhf(gl[256 + g]);
            float ov = sigm(gl[384 + g]);
            c = fv * c + iv * gv;
            float h = ov * tanhf(c);
            hl[g] = h;
            hb[(size_t)t * 128 + g] = h;
        }
        __syncthreads();
        vx = vxn;
    }
}

// ---------------------------------------------------------------------------
// K6: pre-gates layer 1 (weights-stationary): P[b][tl][g] = bih1+bhh1 + Wih1[g]·h0[b][t]
// ---------------------------------------------------------------------------
__global__ __launch_bounds__(512, 2) void k_pre1(const float* __restrict__ H0,
                                                 const float* __restrict__ Wih,
                                                 const float* __restrict__ bih,
                                                 const float* __restrict__ bhh,
                                                 float* __restrict__ P,
                                                 int t0, int TC) {
    const int b = blockIdx.x;
    const int g = threadIdx.x;
    const int lane = g & 63;
    float w[128];
#pragma unroll
    for (int j = 0; j < 128; ++j) w[j] = Wih[(size_t)g * 128 + j];
    const float bias = bih[g] + bhh[g];
    const float* hb = H0 + (size_t)b * 512 * 128 + (size_t)t0 * 128;
    float* pb = P + (size_t)b * TC * 512;
    float vh0 = hb[lane];
    float vh1 = hb[64 + lane];
    for (int tl = 0; tl < TC; ++tl) {
        float nh0 = hb[(size_t)(tl + 1) * 128 + lane];        // prefetch (padded)
        float nh1 = hb[(size_t)(tl + 1) * 128 + 64 + lane];
        float a0 = 0.f, a1 = 0.f, a2 = 0.f, a3 = 0.f;
#pragma unroll
        for (int j = 0; j < 64; j += 4) {
            a0 = fmaf(bcast(vh0, j + 0), w[j + 0], a0);
            a1 = fmaf(bcast(vh0, j + 1), w[j + 1], a1);
            a2 = fmaf(bcast(vh0, j + 2), w[j + 2], a2);
            a3 = fmaf(bcast(vh0, j + 3), w[j + 3], a3);
        }
#pragma unroll
        for (int j = 0; j < 64; j += 4) {
            a0 = fmaf(bcast(vh1, j + 0), w[64 + j + 0], a0);
            a1 = fmaf(bcast(vh1, j + 1), w[64 + j + 1], a1);
            a2 = fmaf(bcast(vh1, j + 2), w[64 + j + 2], a2);
            a3 = fmaf(bcast(vh1, j + 3), w[64 + j + 3], a3);
        }
        pb[(size_t)tl * 512 + g] = bias + ((a0 + a1) + (a2 + a3));
        vh0 = nh0; vh1 = nh1;
    }
}

// ---------------------------------------------------------------------------
// K7: LSTM layer 1 recurrence over one t-chunk; state persists in ws.
// ---------------------------------------------------------------------------
__global__ __launch_bounds__(512, 2) void k_lstm1(const float* __restrict__ P,
                                                  const float* __restrict__ Whh,
                                                  float* __restrict__ Hs,
                                                  float* __restrict__ Cs,
                                                  int TC) {
    __shared__ float hl[128];
    __shared__ float gl[512];
    const int b = blockIdx.x;
    const int g = threadIdx.x;
    const int lane = g & 63;
    float w[128];
#pragma unroll
    for (int j = 0; j < 128; ++j) w[j] = Whh[(size_t)g * 128 + j];
    float c = 0.0f;
    if (g < 128) {
        c = Cs[(size_t)b * 128 + g];
        hl[g] = Hs[(size_t)b * 128 + g];
    }
    __syncthreads();
    const float* pb = P + (size_t)b * TC * 512;
    float vp = pb[g];
    for (int tl = 0; tl < TC; ++tl) {
        float vpn = pb[(size_t)(tl + 1) * 512 + g];   // prefetch (padded)
        float vh0 = hl[lane];
        float vh1 = hl[64 + lane];
        float a0 = 0.f, a1 = 0.f, a2 = 0.f, a3 = 0.f;
#pragma unroll
        for (int j = 0; j < 64; j += 4) {
            a0 = fmaf(bcast(vh0, j + 0), w[j + 0], a0);
            a1 = fmaf(bcast(vh0, j + 1), w[j + 1], a1);
            a2 = fmaf(bcast(vh0, j + 2), w[j + 2], a2);
            a3 = fmaf(bcast(vh0, j + 3), w[j + 3], a3);
        }
#pragma unroll
        for (int j = 0; j < 64; j += 4) {
            a0 = fmaf(bcast(vh1, j + 0), w[64 + j + 0], a0);
            a1 = fmaf(bcast(vh1, j + 1), w[64 + j + 1], a1);
            a2 = fmaf(bcast(vh1, j + 2), w[64 + j + 2], a2);
            a3 = fmaf(bcast(vh1, j + 3), w[64 + j + 3], a3);
        }
        gl[g] = vp + ((a0 + a1) + (a2 + a3));
        __syncthreads();
        if (g < 128) {
            float iv = sigm(gl[g]);
            float fv = sigm(gl[128 + g]);
            float gv = tanhf(gl[256 + g]);
            float ov = sigm(gl[384 + g]);
            c = fv * c + iv * gv;
            float h = ov * tanhf(c);
            hl[g] = h;
        }
        __syncthreads();
        vp = vpn;
    }
    if (g < 128) {
        Hs[(size_t)b * 128 + g] = hl[g];
        Cs[(size_t)b * 128 + g] = c;
    }
}

// ---------------------------------------------------------------------------
// K8: tail head: out = tanh(tanh(h1_last) @ W2^T + b2) @ W3^T + b3
// ---------------------------------------------------------------------------
__global__ __launch_bounds__(64) void k_tail(const float* __restrict__ Hs,
                                             const float* __restrict__ W2,
                                             const float* __restrict__ b2,
                                             const float* __restrict__ W3,
                                             const float* __restrict__ b3,
                                             float* __restrict__ out) {
    __shared__ float last[128], l2s[64];
    const int b = blockIdx.x, tid = threadIdx.x;
    last[tid]      = tanhf(Hs[(size_t)b * 128 + tid]);
    last[tid + 64] = tanhf(Hs[(size_t)b * 128 + 64 + tid]);
    __syncthreads();
    float acc = b2[tid];
#pragma unroll 4
    for (int j = 0; j < 128; ++j) acc = fmaf(W2[(size_t)tid * 128 + j], last[j], acc);
    l2s[tid] = tanhf(acc);
    __syncthreads();
    if (tid < 32) {
        float a2 = b3[tid];
#pragma unroll 4
        for (int o = 0; o < 64; ++o) a2 = fmaf(W3[(size_t)tid * 64 + o], l2s[o], a2);
        out[(size_t)b * 32 + tid] = a2;
    }
}

// ---------------------------------------------------------------------------
extern "C" void kernel_launch(void* const* d_in, const int* in_sizes, int n_in,
                              void* d_out, int out_size, void* d_ws, size_t ws_size,
                              hipStream_t stream) {
    (void)in_sizes; (void)n_in; (void)out_size;
    const float* inp  = (const float*)d_in[0];
    const float* akey = (const float*)d_in[1];
    const float* aval = (const float*)d_in[2];
    const float* W1   = (const float*)d_in[3];
    const float* b1   = (const float*)d_in[4];
    const float* Wih0 = (const float*)d_in[5];
    const float* Whh0 = (const float*)d_in[6];
    const float* bih0 = (const float*)d_in[7];
    const float* bhh0 = (const float*)d_in[8];
    const float* Wih1 = (const float*)d_in[9];
    const float* Whh1 = (const float*)d_in[10];
    const float* bih1 = (const float*)d_in[11];
    const float* bhh1 = (const float*)d_in[12];
    const float* W2   = (const float*)d_in[13];
    const float* b2   = (const float*)d_in[14];
    const float* W3   = (const float*)d_in[15];
    const float* b3   = (const float*)d_in[16];

    float* ws   = (float*)d_ws;
    float* dist = ws;                       // 2,097,152
    float* hist = dist + 2097152;           //   139,264
    float* X    = hist + 139264;            // 8,388,608 + 64 pad
    float* H0   = X + 8388672;              // 16,777,216 + 128 pad
    float* Hs   = H0 + 16777344;            //    32,768
    float* Cs   = Hs + 32768;               //    32,768
    float* P    = Cs + 32768;               // 256*TC*512 + 512 pad
    const size_t fixed = (size_t)(P - ws);

    int TC = 16;  // t-chunk for layer-1 pre-gate buffer, picked from ws_size
    if ((fixed + 131072ull * 128 + 512) * 4 <= ws_size)      TC = 128;
    else if ((fixed + 131072ull * 64 + 512) * 4 <= ws_size)  TC = 64;
    else if ((fixed + 131072ull * 32 + 512) * 4 <= ws_size)  TC = 32;

    k_dist<<<dim3(64, 4), 256, 0, stream>>>(inp, akey, dist);
    k_softmax<<<256, 256, 0, stream>>>(dist);
    hipMemsetAsync(hist, 0, 139264 * 4, stream);
    k_hist<<<dim3(9, 4, 8), 256, 0, stream>>>(dist, aval, hist);
    k_xfeat<<<dim3(4, 256), 256, 0, stream>>>(inp, hist, W1, b1, X);
    k_lstm0<<<256, 512, 0, stream>>>(X, Wih0, Whh0, bih0, bhh0, H0);
    hipMemsetAsync(Hs, 0, 65536 * 4, stream);  // zero Hs+Cs (contiguous)
    for (int t0 = 0; t0 < 512; t0 += TC) {
        k_pre1<<<256, 512, 0, stream>>>(H0, Wih1, bih1, bhh1, P, t0, TC);
        k_lstm1<<<256, 512, 0, stream>>>(P, Whh1, Hs, Cs, TC);
    }
    k_tail<<<256, 64, 0, stream>>>(Hs, W2, b2, W3, b3, (float*)d_out);
}